// Round 13
// baseline (72.347 us; speedup 1.0000x reference)
//
#include <hip/hip_runtime.h>
#include <hip/hip_bf16.h>
#include <stdint.h>

typedef __attribute__((ext_vector_type(8))) short short8;
typedef __attribute__((ext_vector_type(4))) float f32x4;

__device__ inline unsigned short f2bf(float f) {
  union { float f; unsigned u; } v; v.f = f;
  unsigned r = v.u + 0x7fffu + ((v.u >> 16) & 1u);
  return (unsigned short)(r >> 16);
}
__device__ inline float bf2f(unsigned short u) {
  union { unsigned u; float f; } v; v.u = ((unsigned)u) << 16; return v.f;
}

// -------- kernel 1: MERGED prep: blocks 0..255 build T (bf16), 256..2303 conv ----
// (R11-measured: ~17 us, conv at ~90% of achievable HBM BW)
__global__ __launch_bounds__(256) void tt_prep(
    const float* __restrict__ x, const float* __restrict__ filt,
    const float* __restrict__ c0, const float* __restrict__ c1,
    const float* __restrict__ c2, const float* __restrict__ c3,
    unsigned short* __restrict__ Tb, unsigned short* __restrict__ D) {
  __shared__ __align__(16) char smem[40960];
  const int tid = threadIdx.x;
  const int bid = blockIdx.x;

  if (bid < 256) {
    unsigned short* Lb = (unsigned short*)smem;
    unsigned short* Rb = (unsigned short*)(smem + 16384);
    for (int i = tid; i < 8192; i += 256) {
      int n1 = i & 7, n0 = (i >> 3) & 3, r2 = (i >> 5) & 7, m1 = (i >> 8) & 7, m0 = i >> 11;
      float s = 0.f;
#pragma unroll
      for (int r1 = 0; r1 < 8; ++r1)
        s += c0[(m0 * 8 + r1) * 4 + n0] * c1[(m1 * 8 + r2) * 64 + r1 * 8 + n1];
      Lb[i] = f2bf(s);
    }
    for (int i = tid; i < 8192; i += 256) {
      int n3 = i & 3, n2 = (i >> 2) & 7, m3 = (i >> 5) & 3, m2 = (i >> 7) & 7, r2 = i >> 10;
      float s = 0.f;
#pragma unroll
      for (int r3 = 0; r3 < 8; ++r3)
        s += c2[(m2 * 8 + r3) * 64 + r2 * 8 + n2] * c3[m3 * 32 + r3 * 4 + n3];
      Rb[i] = f2bf(s);
    }
    __syncthreads();
    int base = bid * 4096;
    for (int j = 0; j < 16; ++j) {
      int g = base + j * 256 + tid;
      int m = g >> 10, n = g & 1023;
      int m0 = m >> 8, m1 = (m >> 5) & 7, m2 = (m >> 2) & 7, m3 = m & 3;
      int n0 = n >> 8, n1 = (n >> 5) & 7, n2 = (n >> 2) & 7, n3 = n & 3;
      float s = 0.f;
#pragma unroll
      for (int r2 = 0; r2 < 8; ++r2)
        s += bf2f(Lb[(((m0 * 8 + m1) * 8 + r2) * 4 + n0) * 8 + n1]) *
             bf2f(Rb[(((r2 * 8 + m2) * 4 + m3) * 8 + n2) * 4 + n3]);
      Tb[(size_t)m * 1024 + n] = f2bf(s);
    }
    return;
  }

  float (*xs)[32][32] = (float(*)[32][32])smem;
  int cb = bid - 256;
  int cg = cb & 31, strip = (cb >> 5) & 3, b = cb >> 7;
  int h0 = strip * 8;
  float4 z4; z4.x = z4.y = z4.z = z4.w = 0.f;
#pragma unroll
  for (int i = 0; i < 10; ++i) {
    int j = tid + 256 * i;
    int row = j >> 8, w = (j >> 3) & 31, c4 = j & 7;
    int gh = h0 - 1 + row;
    float4 v = z4;
    if ((unsigned)gh < 32u)
      v = *reinterpret_cast<const float4*>(x + ((size_t)((b * 32 + gh) * 32 + w)) * 1024 + cg * 32 + c4 * 4);
    *reinterpret_cast<float4*>(&xs[row][w][c4 * 4]) = v;
  }
  float F[9];
#pragma unroll
  for (int i = 0; i < 9; ++i) F[i] = filt[i];
  __syncthreads();

  int c4 = tid & 7, w = tid >> 3;
#define LD3(r, d0, d1, d2) { \
    d1 = *reinterpret_cast<const float4*>(&xs[r][w][c4 * 4]); \
    d0 = (w > 0)  ? *reinterpret_cast<const float4*>(&xs[r][w - 1][c4 * 4]) : z4; \
    d2 = (w < 31) ? *reinterpret_cast<const float4*>(&xs[r][w + 1][c4 * 4]) : z4; }
#define ACC4(a, f, v) { a.x += (f) * v.x; a.y += (f) * v.y; a.z += (f) * v.z; a.w += (f) * v.w; }
  float4 a00, a01, a02, a10, a11, a12, a20, a21, a22;
  LD3(0, a00, a01, a02);
  LD3(1, a10, a11, a12);
#pragma unroll
  for (int h = 0; h < 8; ++h) {
    LD3(h + 2, a20, a21, a22);
    float4 s = z4;
    ACC4(s, F[0], a00); ACC4(s, F[1], a01); ACC4(s, F[2], a02);
    ACC4(s, F[3], a10); ACC4(s, F[4], a11); ACC4(s, F[5], a12);
    ACC4(s, F[6], a20); ACC4(s, F[7], a21); ACC4(s, F[8], a22);
    ushort4 o;
    o.x = f2bf(s.x); o.y = f2bf(s.y); o.z = f2bf(s.z); o.w = f2bf(s.w);
    *reinterpret_cast<ushort4*>(&D[((size_t)(b * 1024 + (h0 + h) * 32 + w)) * 1024 + cg * 32 + c4 * 4]) = o;
    a00 = a10; a01 = a11; a02 = a12;
    a10 = a20; a11 = a21; a12 = a22;
  }
#undef LD3
#undef ACC4
}

// -------- kernel 2: R4's tt_gemm_p3 VERBATIM (best measured: 53.1-53.9 us) ----
// 256x256 tile, BK=32, 3-buffer LDS ring, split staging, counted vmcnt(6),
// row-pair XOR swizzle via pre-swizzled global source (0 bank conflicts),
// operand-swapped MFMA -> f32x4 C stores.
__device__ inline void stage16(const unsigned short* g, unsigned short* l) {
  __builtin_amdgcn_global_load_lds(
      (const __attribute__((address_space(1))) void*)g,
      (__attribute__((address_space(3))) void*)l, 16, 0, 0);
}

__global__ __launch_bounds__(512, 2) void tt_gemm_p3(
    const unsigned short* __restrict__ A,   // [16384, 1024] bf16
    const unsigned short* __restrict__ Bt,  // [1024, 1024] bf16
    const float* __restrict__ bias,
    float* __restrict__ C) {
  __shared__ unsigned short lds[3][2][8192];  // [ring][A/B][256 rows x 32 k], 96 KiB
  const int tid = threadIdx.x;
  const int lane = tid & 63, wave = tid >> 6;
  const int wr = wave >> 2, wc = wave & 3;      // 2M x 4N waves, per-wave 128x64
  const int lr = lane & 15, kc = lane >> 4;
  const int rg = kc;

  int lin = blockIdx.x + blockIdx.y * 64;
  int Lg = ((lin & 7) << 5) | (lin >> 3);
  int brow = (Lg & 63) * 256;
  int bcol = (Lg >> 6) * 256;

  int rowq0, cq0, rowq1, cq1;
  { int q = tid;       int li = q >> 3, sp = q & 7, sl = sp ^ (li & 7); rowq0 = 2 * li + (sl >> 2); cq0 = sl & 3; }
  { int q = tid + 512; int li = q >> 3, sp = q & 7, sl = sp ^ (li & 7); rowq1 = 2 * li + (sl >> 2); cq1 = sl & 3; }
  const unsigned short* srcA0 = A + (size_t)(brow + rowq0) * 1024 + cq0 * 8;
  const unsigned short* srcA1 = A + (size_t)(brow + rowq1) * 1024 + cq1 * 8;
  const unsigned short* srcB0 = Bt + (size_t)(bcol + rowq0) * 1024 + cq0 * 8;
  const unsigned short* srcB1 = Bt + (size_t)(bcol + rowq1) * 1024 + cq1 * 8;
  const int l0 = tid * 8, l1 = (tid + 512) * 8;

  int offA[8], offB[4];
#pragma unroll
  for (int m = 0; m < 8; ++m) {
    int row = wr * 128 + m * 16 + lr;
    int li = row >> 1, sl = (row & 1) * 4 + kc;
    offA[m] = (li * 8 + (sl ^ (li & 7))) * 8;
  }
#pragma unroll
  for (int n = 0; n < 4; ++n) {
    int row = wc * 64 + n * 16 + lr;
    int li = row >> 1, sl = (row & 1) * 4 + kc;
    offB[n] = (li * 8 + (sl ^ (li & 7))) * 8;
  }

  f32x4 acc[8][4] = {};

#define STAGE_B(S, T) { stage16(srcB0 + (T) * 32, &lds[S][1][l0]); \
                        stage16(srcB1 + (T) * 32, &lds[S][1][l1]); }
#define STAGE_A(S, T) { stage16(srcA0 + (T) * 32, &lds[S][0][l0]); \
                        stage16(srcA1 + (T) * 32, &lds[S][0][l1]); }

#define KTILE(RB, SB, T2, VMS) { \
    short8 bfr[4]; \
    if ((T2) >= 0) STAGE_B(SB, T2); \
    asm volatile("s_waitcnt vmcnt(" VMS ")" ::: "memory"); \
    __builtin_amdgcn_s_barrier(); \
    { short8 af[4]; \
      _Pragma("unroll") for (int m = 0; m < 4; ++m) \
        af[m] = *reinterpret_cast<const short8*>(&lds[RB][0][offA[m]]); \
      _Pragma("unroll") for (int n = 0; n < 4; ++n) \
        bfr[n] = *reinterpret_cast<const short8*>(&lds[RB][1][offB[n]]); \
      asm volatile("s_waitcnt lgkmcnt(0)"); \
      __builtin_amdgcn_s_setprio(1); \
      _Pragma("unroll") for (int m = 0; m < 4; ++m) \
        _Pragma("unroll") for (int n = 0; n < 4; ++n) \
          acc[m][n] = __builtin_amdgcn_mfma_f32_16x16x32_bf16(bfr[n], af[m], acc[m][n], 0, 0, 0); \
      __builtin_amdgcn_s_setprio(0); } \
    __builtin_amdgcn_s_barrier(); \
    if ((T2) >= 0) STAGE_A(SB, T2); \
    __builtin_amdgcn_s_barrier(); \
    { short8 af[4]; \
      _Pragma("unroll") for (int m = 0; m < 4; ++m) \
        af[m] = *reinterpret_cast<const short8*>(&lds[RB][0][offA[4 + m]]); \
      asm volatile("s_waitcnt lgkmcnt(0)"); \
      __builtin_amdgcn_s_setprio(1); \
      _Pragma("unroll") for (int m = 0; m < 4; ++m) \
        _Pragma("unroll") for (int n = 0; n < 4; ++n) \
          acc[4 + m][n] = __builtin_amdgcn_mfma_f32_16x16x32_bf16(bfr[n], af[m], acc[4 + m][n], 0, 0, 0); \
      __builtin_amdgcn_s_setprio(0); } \
    __builtin_amdgcn_s_barrier(); }

  STAGE_B(0, 0); STAGE_A(0, 0);
  STAGE_B(1, 1); STAGE_A(1, 1);

  for (int t = 0; t < 30; t += 3) {
    KTILE(0, 2, t + 2, "6")
    KTILE(1, 0, t + 3, "6")
    KTILE(2, 1, t + 4, "6")
  }
  KTILE(0, 0, -1, "4")
  KTILE(1, 1, -1, "0")

#undef KTILE
#undef STAGE_A
#undef STAGE_B

#pragma unroll
  for (int n = 0; n < 4; ++n) {
    int col = bcol + wc * 64 + n * 16 + rg * 4;
    float4 bv = *reinterpret_cast<const float4*>(&bias[col]);
#pragma unroll
    for (int m = 0; m < 8; ++m) {
      int row = brow + wr * 128 + m * 16 + lr;
      f32x4 v = acc[m][n];
      float4 o;
      o.x = v[0] + bv.x; o.y = v[1] + bv.y; o.z = v[2] + bv.z; o.w = v[3] + bv.w;
      o.x = o.x > 0.f ? o.x : 0.f;
      o.y = o.y > 0.f ? o.y : 0.f;
      o.z = o.z > 0.f ? o.z : 0.f;
      o.w = o.w > 0.f ? o.w : 0.f;
      *reinterpret_cast<float4*>(&C[(size_t)row * 1024 + col]) = o;
    }
  }
}

extern "C" void kernel_launch(void* const* d_in, const int* in_sizes, int n_in,
                              void* d_out, int out_size, void* d_ws, size_t ws_size,
                              hipStream_t stream) {
  const float* x = (const float*)d_in[0];
  const float* filt = (const float*)d_in[1];
  const float* c0 = (const float*)d_in[2];
  const float* c1 = (const float*)d_in[3];
  const float* c2 = (const float*)d_in[4];
  const float* c3 = (const float*)d_in[5];
  const float* bias = (const float*)d_in[6];
  float* out = (float*)d_out;

  unsigned short* Tb = (unsigned short*)d_ws;        // 2 MB
  unsigned short* D = Tb + (size_t)1024 * 1024;      // 32 MB

  tt_prep<<<2304, 256, 0, stream>>>(x, filt, c0, c1, c2, c3, Tb, D);
  dim3 grid(64, 4);
  tt_gemm_p3<<<grid, 512, 0, stream>>>(D, Tb, bias, out);
}